// Round 10
// baseline (322.618 us; speedup 1.0000x reference)
//
#include <hip/hip_runtime.h>

#define IMG_H 480
#define IMG_W 640
#define OUT_H 470    // 480 - 10
#define OUT_W 630    // 640 - 10
#define NBATCH 32
#define SW 118       // output columns per wave (128 input cols - 10 halo)
#define NSTRIPE 6    // ceil(630 / 118)
#define RCH 47       // output rows per wave-chunk (47 * 10 = 470 exact)
#define NCHUNK 10
#define NROWS (RCH + 10)   // 57 input rows per chunk

#define SSIM_C1 1.0f // (0.01*100)^2
#define SSIM_C2 9.0f // (0.03*100)^2

typedef float v2f __attribute__((ext_vector_type(2)));

// Normalized 11-tap Gaussian (sigma=1.5), matches numpy fp32 window to ~1e-7 rel.
__device__ constexpr float WG[11] = {
    0.00102838f, 0.00759876f, 0.03600077f, 0.10936068f, 0.21300554f,
    0.26601173f,
    0.21300554f, 0.10936068f, 0.03600077f, 0.00759876f, 0.00102838f
};

// lane+j neighbor fetch via ds_bpermute (register crossbar, no LDS storage,
// no barriers). Wrap for lane+j>63 returns in-wave data (finite), masked by
// the validity predicates.
__device__ __forceinline__ float lane_shift(int baddr, int j, float v) {
    return __int_as_float(
        __builtin_amdgcn_ds_bpermute(baddr + (j << 2), __float_as_int(v)));
}

// Packed fp32 fma: llvm.fma.v2f32 -> v_pk_fma_f32 (2 FLOP-pairs per issue slot)
__device__ __forceinline__ v2f pk_fma(v2f a, v2f b, v2f c) {
    return __builtin_elementwise_fma(a, b, c);
}

// One phase, software-pipelined two levels deep:
//   VMEM: row IT+2 global prefetch issued here, consumed in 2 phases
//   DS:   row IT+1 bpermute gather issued here into pv[(IT+1)&1],
//         consumed next phase (latency hidden under this phase's VALU)
//   VALU: h-pass + ring + epilogue on pv[IT&1] (row IT)
// IT is a post-unroll literal: all %/& index math folds; pv/acc stay in regs.
// REGISTER BUDGET (R4/R5/R7 lesson): ring 55 + pv 48 + c/n 16 + ~25 working
// ≈ 145 regs. __launch_bounds__(64,2) -> 256-reg cap (fits with slack).
// waves/EU=3 (170 cap) is borderline -> keep 2. Sentinel: WRITE_SIZE ~60 KB.
#define STEP(IT)                                                              \
  {                                                                           \
    const int P   = (IT) % 11;                                                \
    const int cur = (IT) & 1;                                                 \
    const int nxt = ((IT) + 1) & 1;                                           \
    /* 1. global prefetch row IT+2 (branch folds: IT is literal) */           \
    float2 n1 = make_float2(0.f, 0.f), n2 = n1;                               \
    if ((IT) + 2 < NROWS) {                                                   \
      int gy = y0 + (IT) + 2; if (gy > IMG_H - 1) gy = IMG_H - 1;             \
      n1 = *(const float2*)(p1 + gy * IMG_W + colA);                          \
      n2 = *(const float2*)(p2 + gy * IMG_W + colA);                          \
    }                                                                         \
    /* 2. DS gather row IT+1 (c holds it) into pv[nxt]; 20 bpermutes whose */ \
    /*    latency retires under step 3's ~400 VALU cycles */                  \
    if ((IT) + 1 < NROWS) {                                                   \
      pv[nxt][0] = (v2f){c1.x, c2.x};                                         \
      pv[nxt][1] = (v2f){c1.y, c2.y};                                         \
      _Pragma("unroll")                                                       \
      for (int j = 1; j <= 5; ++j) {                                          \
        pv[nxt][2*j]   = (v2f){lane_shift(baddr, j, c1.x),                    \
                               lane_shift(baddr, j, c2.x)};                   \
        pv[nxt][2*j+1] = (v2f){lane_shift(baddr, j, c1.y),                    \
                               lane_shift(baddr, j, c2.y)};                   \
      }                                                                       \
    }                                                                         \
    /* 3a. horizontal 11-tap pass on pv[cur], packed (img1,img2) */           \
    v2f ph[2], phs[2]; float ph12[2];                                         \
    ph[0] = (v2f){0.f,0.f}; ph[1] = (v2f){0.f,0.f};                           \
    phs[0] = (v2f){0.f,0.f}; phs[1] = (v2f){0.f,0.f};                         \
    ph12[0] = 0.f; ph12[1] = 0.f;                                             \
    _Pragma("unroll")                                                         \
    for (int j = 0; j < 11; ++j) {                                            \
      const v2f wj = (v2f){WG[j], WG[j]};                                     \
      _Pragma("unroll")                                                       \
      for (int s = 0; s < 2; ++s) {                                           \
        const v2f v = pv[cur][j + s];                                         \
        const v2f t = wj * v;              /* pk_mul: (w*v1, w*v2) */         \
        ph[s] += t;                        /* pk_add: (h1, h2)     */         \
        phs[s] = pk_fma(t, v, phs[s]);     /* pk_fma: (h11, h22)   */         \
        ph12[s] = fmaf(t.x, v.y, ph12[s]); /* scalar: h12          */         \
      }                                                                       \
    }                                                                         \
    /* 3b. vertical ring update: per slot per col = 2 pk_fma + 1 fma */       \
    _Pragma("unroll")                                                         \
    for (int sl = 0; sl < 11; ++sl) {                                         \
      const float wt = WG[(P - sl + 11) % 11];                                \
      const v2f wv = (v2f){wt, wt};                                           \
      _Pragma("unroll")                                                       \
      for (int s = 0; s < 2; ++s) {                                           \
        acc_mu[sl][s] = pk_fma(wv, ph[s],  acc_mu[sl][s]);                    \
        acc_sq[sl][s] = pk_fma(wv, phs[s], acc_sq[sl][s]);                    \
        acc_x[sl][s]  = fmaf(wt, ph12[s],  acc_x[sl][s]);                     \
      }                                                                       \
    }                                                                         \
    /* 3c. slot sc got its w[10] tap -> output row y = IT-10 completes */     \
    const int sc = (P + 1) % 11;                                              \
    const int y = (IT) - 10;                                                  \
    if ((IT) >= 10 && (y0 + y) < OUT_H) {                                     \
      _Pragma("unroll")                                                       \
      for (int s = 0; s < 2; ++s) {                                           \
        if (s == 0 ? validA : validB) {                                       \
          const v2f m = acc_mu[sc][s];        /* (mu1, mu2) */                \
          const v2f msq = m * m;              /* (mu1^2, mu2^2) */            \
          const float mu12 = m.x * m.y;                                       \
          const v2f sg = acc_sq[sc][s] - msq; /* (sg1, sg2) */                \
          const float vA = fmaf(2.f, acc_x[sc][s] - mu12, SSIM_C2);           \
          const float vB = sg.x + sg.y + SSIM_C2;                             \
          const float num = fmaf(2.f, mu12, SSIM_C1) * vA;                    \
          const float den = (msq.x + msq.y + SSIM_C1) * vB;                   \
          lsum = fmaf(num, __builtin_amdgcn_rcpf(den), lsum);                 \
        }                                                                     \
      }                                                                       \
    }                                                                         \
    _Pragma("unroll")                                                         \
    for (int s = 0; s < 2; ++s) {                                             \
      acc_mu[sc][s] = (v2f){0.f,0.f};                                         \
      acc_sq[sc][s] = (v2f){0.f,0.f};                                         \
      acc_x[sc][s]  = 0.f;                                                    \
    }                                                                         \
    /* 4. roll the global-load pipeline */                                    \
    c1 = n1; c2 = n2;                                                         \
  }

__global__ __launch_bounds__(64, 2) void ssim_main(
    const float* __restrict__ img1,
    const float* __restrict__ img2,
    float* __restrict__ partials)
{
    const int lane   = threadIdx.x;
    const int stripe = blockIdx.x;
    const int cy     = blockIdx.y;
    const int b      = blockIdx.z;
    const int x0 = SW * stripe;
    const int y0 = RCH * cy;

    const float* __restrict__ p1 = img1 + (size_t)b * (IMG_H * IMG_W);
    const float* __restrict__ p2 = img2 + (size_t)b * (IMG_H * IMG_W);

    // lane owns input cols (x0+2l, x0+2l+1); clamp keeps 8B alignment
    int colA = x0 + 2 * lane;  if (colA > IMG_W - 2) colA = IMG_W - 2;
    const int baddr = lane << 2;

    // lane l consumes input cols 2l..2l+11 -> lanes 0..58 produce valid outputs
    const bool validA = (lane < 59) && (x0 + 2 * lane     < OUT_W);
    const bool validB = (lane < 59) && (x0 + 2 * lane + 1 < OUT_W);

    // vertical ring: (mu1,mu2) pk, (s11,s22) pk, s12 scalar, per 2 cols
    v2f acc_mu[11][2], acc_sq[11][2];
    float acc_x[11][2];
#pragma unroll
    for (int i = 0; i < 11; ++i)
#pragma unroll
        for (int s = 0; s < 2; ++s) {
            acc_mu[i][s] = (v2f){0.f, 0.f};
            acc_sq[i][s] = (v2f){0.f, 0.f};
            acc_x[i][s] = 0.f;
        }

    float lsum = 0.f;

    // gather ping-pong: pv[parity][12] holds one gathered input row (packed)
    v2f pv[2][12];

    // prologue: row 0 -> gather into pv[0]; row 1 -> c (gathered at STEP(0))
    float2 c1, c2;
    {
        const float2 r1 = *(const float2*)(p1 + y0 * IMG_W + colA);
        const float2 r2 = *(const float2*)(p2 + y0 * IMG_W + colA);
        pv[0][0] = (v2f){r1.x, r2.x};
        pv[0][1] = (v2f){r1.y, r2.y};
#pragma unroll
        for (int j = 1; j <= 5; ++j) {
            pv[0][2*j]   = (v2f){lane_shift(baddr, j, r1.x),
                                 lane_shift(baddr, j, r2.x)};
            pv[0][2*j+1] = (v2f){lane_shift(baddr, j, r1.y),
                                 lane_shift(baddr, j, r2.y)};
        }
        c1 = *(const float2*)(p1 + (y0 + 1) * IMG_W + colA);
        c2 = *(const float2*)(p2 + (y0 + 1) * IMG_W + colA);
    }

    // 57 input rows: 5 full 11-phase blocks + 2 tail phases
    for (int blk = 0; blk < 5; ++blk) {
        const int base = blk * 11;
#pragma unroll
        for (int p = 0; p < 11; ++p) STEP(base + p)
    }
    {
        const int base = 55;
#pragma unroll
        for (int p = 0; p < 2; ++p) STEP(base + p)
    }

    // wave-level reduction (64 lanes)
#pragma unroll
    for (int off = 32; off > 0; off >>= 1)
        lsum += __shfl_down(lsum, off);
    if (lane == 0)
        partials[(b * NCHUNK + cy) * NSTRIPE + stripe] = lsum;
}

__global__ __launch_bounds__(256) void ssim_reduce(
    const float* __restrict__ partials, float* __restrict__ out)
{
    const int n = NSTRIPE * NCHUNK * NBATCH;  // 1920
    __shared__ double red[256];
    int tid = threadIdx.x;
    double s = 0.0;
    for (int i = tid; i < n; i += 256) s += (double)partials[i];
    red[tid] = s;
    __syncthreads();
    for (int k = 128; k > 0; k >>= 1) {
        if (tid < k) red[tid] += red[tid + k];
        __syncthreads();
    }
    if (tid == 0) {
        double mean = red[0] / (double)((size_t)NBATCH * OUT_H * OUT_W);
        out[0] = (float)((1.0 - mean) * 0.5);
    }
}

extern "C" void kernel_launch(void* const* d_in, const int* in_sizes, int n_in,
                              void* d_out, int out_size, void* d_ws, size_t ws_size,
                              hipStream_t stream)
{
    const float* img1 = (const float*)d_in[0];
    const float* img2 = (const float*)d_in[1];
    float* out = (float*)d_out;
    float* partials = (float*)d_ws;  // 1920 floats = 7.7 KB

    dim3 grid(NSTRIPE, NCHUNK, NBATCH);  // 6 x 10 x 32 = 1920 single-wave blocks
    ssim_main<<<grid, dim3(64), 0, stream>>>(img1, img2, partials);
    ssim_reduce<<<1, dim3(256), 0, stream>>>(partials, out);
}

// Round 11
// 134.299 us; speedup vs baseline: 2.4022x; 2.4022x over previous
//
#include <hip/hip_runtime.h>

#define IMG_H 480
#define IMG_W 640
#define OUT_H 470    // 480 - 10
#define OUT_W 630    // 640 - 10
#define NBATCH 32
#define SW 118       // output columns per wave (128 input cols - 10 halo)
#define NSTRIPE 6    // ceil(630 / 118)
#define RCH 47       // output rows per wave-chunk (47 * 10 = 470 exact)
#define NCHUNK 10
#define NROWS (RCH + 10)   // 57 input rows per chunk

#define SSIM_C1 1.0f // (0.01*100)^2
#define SSIM_C2 9.0f // (0.03*100)^2

typedef float v2f __attribute__((ext_vector_type(2)));

// Normalized 11-tap Gaussian (sigma=1.5), matches numpy fp32 window to ~1e-7 rel.
__device__ constexpr float WG[11] = {
    0.00102838f, 0.00759876f, 0.03600077f, 0.10936068f, 0.21300554f,
    0.26601173f,
    0.21300554f, 0.10936068f, 0.03600077f, 0.00759876f, 0.00102838f
};

// lane+j neighbor fetch via ds_bpermute (register crossbar, no LDS storage,
// no barriers). Wrap for lane+j>63 returns in-wave data (finite), masked by
// the validity predicates.
__device__ __forceinline__ float lane_shift(int baddr, int j, float v) {
    return __int_as_float(
        __builtin_amdgcn_ds_bpermute(baddr + (j << 2), __float_as_int(v)));
}

// Packed fp32 fma: llvm.fma.v2f32 -> v_pk_fma_f32 (2 FLOP-pairs per issue slot)
__device__ __forceinline__ v2f pk_fma(v2f a, v2f b, v2f c) {
    return __builtin_elementwise_fma(a, b, c);
}

// One phase, software-pipelined two levels deep:
//   VMEM: row IT+2 global prefetch issued here (clamped, unconditional)
//   DS:   row IT+1 gather issued into pv[(PP+1)&1], consumed next phase
//   VALU: h-pass + ring + epilogue on pv[PP&1] (row IT)
//
// *** INDEXING MUST BE COMPILE-TIME (R10 lesson) ***
// R10 computed P/parity from a runtime base -> dynamic acc[]/pv[] indexing
// -> both arrays demoted to scratch -> WRITE_SIZE 598 MB, 252 us. PP below
// is a post-unroll LITERAL (inner unroll length 22 ≡ 0 mod 11 and even, so
// P = PP%11 and parity = PP&1 are correct for any runtime base). IT is used
// only for addresses / wave-uniform bounds tests (runtime OK).
// REGISTER BUDGET (R4/R5/R7): ring 55 + pv 48 + c/n 8 + ~35 working ≈ 145.
// __launch_bounds__(64,2) -> 256-reg cap. Sentinel: WRITE_SIZE ~60 KB.
#define STEP(IT, PP)                                                          \
  {                                                                           \
    const int P   = (PP) % 11;                                                \
    const int cur = (PP) & 1;                                                 \
    const int nxt = ((PP) + 1) & 1;                                           \
    /* 1. global prefetch row IT+2 (clamped; harmless tail overshoot) */      \
    int gy = y0 + (IT) + 2; if (gy > IMG_H - 1) gy = IMG_H - 1;               \
    const float2 n1 = *(const float2*)(p1 + gy * IMG_W + colA);               \
    const float2 n2 = *(const float2*)(p2 + gy * IMG_W + colA);               \
    /* 2. DS gather row IT+1 (held in c) into pv[nxt]; latency retires */     \
    /*    under this phase's ~400 VALU cycles */                              \
    pv[nxt][0] = (v2f){c1.x, c2.x};                                           \
    pv[nxt][1] = (v2f){c1.y, c2.y};                                           \
    _Pragma("unroll")                                                         \
    for (int j = 1; j <= 5; ++j) {                                            \
      pv[nxt][2*j]   = (v2f){lane_shift(baddr, j, c1.x),                      \
                             lane_shift(baddr, j, c2.x)};                     \
      pv[nxt][2*j+1] = (v2f){lane_shift(baddr, j, c1.y),                      \
                             lane_shift(baddr, j, c2.y)};                     \
    }                                                                         \
    /* 3a. horizontal 11-tap pass on pv[cur], packed (img1,img2) */           \
    v2f ph[2], phs[2]; float ph12[2];                                         \
    ph[0] = (v2f){0.f,0.f}; ph[1] = (v2f){0.f,0.f};                           \
    phs[0] = (v2f){0.f,0.f}; phs[1] = (v2f){0.f,0.f};                         \
    ph12[0] = 0.f; ph12[1] = 0.f;                                             \
    _Pragma("unroll")                                                         \
    for (int j = 0; j < 11; ++j) {                                            \
      const v2f wj = (v2f){WG[j], WG[j]};                                     \
      _Pragma("unroll")                                                       \
      for (int s = 0; s < 2; ++s) {                                           \
        const v2f v = pv[cur][j + s];                                         \
        const v2f t = wj * v;              /* pk_mul: (w*v1, w*v2) */         \
        ph[s] += t;                        /* pk_add: (h1, h2)     */         \
        phs[s] = pk_fma(t, v, phs[s]);     /* pk_fma: (h11, h22)   */         \
        ph12[s] = fmaf(t.x, v.y, ph12[s]); /* scalar: h12          */         \
      }                                                                       \
    }                                                                         \
    /* 3b. vertical ring update: per slot per col = 2 pk_fma + 1 fma */       \
    _Pragma("unroll")                                                         \
    for (int sl = 0; sl < 11; ++sl) {                                         \
      const float wt = WG[(P - sl + 11) % 11];                                \
      const v2f wv = (v2f){wt, wt};                                           \
      _Pragma("unroll")                                                       \
      for (int s = 0; s < 2; ++s) {                                           \
        acc_mu[sl][s] = pk_fma(wv, ph[s],  acc_mu[sl][s]);                    \
        acc_sq[sl][s] = pk_fma(wv, phs[s], acc_sq[sl][s]);                    \
        acc_x[sl][s]  = fmaf(wt, ph12[s],  acc_x[sl][s]);                     \
      }                                                                       \
    }                                                                         \
    /* 3c. slot sc got its w[10] tap -> output row y = IT-10 completes */     \
    const int sc = (P + 1) % 11;                                              \
    if ((IT) >= 10 && (y0 + (IT) - 10) < OUT_H) {                             \
      _Pragma("unroll")                                                       \
      for (int s = 0; s < 2; ++s) {                                           \
        if (s == 0 ? validA : validB) {                                       \
          const v2f m = acc_mu[sc][s];        /* (mu1, mu2) */                \
          const v2f msq = m * m;              /* (mu1^2, mu2^2) */            \
          const float mu12 = m.x * m.y;                                       \
          const v2f sg = acc_sq[sc][s] - msq; /* (sg1, sg2) */                \
          const float vA = fmaf(2.f, acc_x[sc][s] - mu12, SSIM_C2);           \
          const float vB = sg.x + sg.y + SSIM_C2;                             \
          const float num = fmaf(2.f, mu12, SSIM_C1) * vA;                    \
          const float den = (msq.x + msq.y + SSIM_C1) * vB;                   \
          lsum = fmaf(num, __builtin_amdgcn_rcpf(den), lsum);                 \
        }                                                                     \
      }                                                                       \
    }                                                                         \
    _Pragma("unroll")                                                         \
    for (int s = 0; s < 2; ++s) {                                             \
      acc_mu[sc][s] = (v2f){0.f,0.f};                                         \
      acc_sq[sc][s] = (v2f){0.f,0.f};                                         \
      acc_x[sc][s]  = 0.f;                                                    \
    }                                                                         \
    /* 4. roll the global-load pipeline */                                    \
    c1 = n1; c2 = n2;                                                         \
  }

__global__ __launch_bounds__(64, 2) void ssim_main(
    const float* __restrict__ img1,
    const float* __restrict__ img2,
    float* __restrict__ partials)
{
    const int lane   = threadIdx.x;
    const int stripe = blockIdx.x;
    const int cy     = blockIdx.y;
    const int b      = blockIdx.z;
    const int x0 = SW * stripe;
    const int y0 = RCH * cy;

    const float* __restrict__ p1 = img1 + (size_t)b * (IMG_H * IMG_W);
    const float* __restrict__ p2 = img2 + (size_t)b * (IMG_H * IMG_W);

    // lane owns input cols (x0+2l, x0+2l+1); clamp keeps 8B alignment
    int colA = x0 + 2 * lane;  if (colA > IMG_W - 2) colA = IMG_W - 2;
    const int baddr = lane << 2;

    // lane l consumes input cols 2l..2l+11 -> lanes 0..58 produce valid outputs
    const bool validA = (lane < 59) && (x0 + 2 * lane     < OUT_W);
    const bool validB = (lane < 59) && (x0 + 2 * lane + 1 < OUT_W);

    // vertical ring: (mu1,mu2) pk, (s11,s22) pk, s12 scalar, per 2 cols
    v2f acc_mu[11][2], acc_sq[11][2];
    float acc_x[11][2];
#pragma unroll
    for (int i = 0; i < 11; ++i)
#pragma unroll
        for (int s = 0; s < 2; ++s) {
            acc_mu[i][s] = (v2f){0.f, 0.f};
            acc_sq[i][s] = (v2f){0.f, 0.f};
            acc_x[i][s] = 0.f;
        }

    float lsum = 0.f;

    // gather ping-pong: pv[parity][12] holds one gathered input row (packed)
    v2f pv[2][12];

    // prologue: row 0 -> gather into pv[0]; row 1 -> c (gathered at STEP 0)
    float2 c1, c2;
    {
        const float2 r1 = *(const float2*)(p1 + y0 * IMG_W + colA);
        const float2 r2 = *(const float2*)(p2 + y0 * IMG_W + colA);
        pv[0][0] = (v2f){r1.x, r2.x};
        pv[0][1] = (v2f){r1.y, r2.y};
#pragma unroll
        for (int j = 1; j <= 5; ++j) {
            pv[0][2*j]   = (v2f){lane_shift(baddr, j, r1.x),
                                 lane_shift(baddr, j, r2.x)};
            pv[0][2*j+1] = (v2f){lane_shift(baddr, j, r1.y),
                                 lane_shift(baddr, j, r2.y)};
        }
        c1 = *(const float2*)(p1 + (y0 + 1) * IMG_W + colA);
        c2 = *(const float2*)(p2 + (y0 + 1) * IMG_W + colA);
    }

    // 57 rows: runtime loop of 2 x 22-step unroll (22 ≡ 0 mod 11, even ->
    // P and parity fold to literals inside), then literal-base tail of 13.
    for (int blk = 0; blk < 2; ++blk) {
        const int base = 22 * blk;
#pragma unroll
        for (int p = 0; p < 22; ++p) STEP(base + p, p)
    }
#pragma unroll
    for (int p = 0; p < 13; ++p) STEP(44 + p, p)   // 44 % 11 == 0, 44 even

    // wave-level reduction (64 lanes)
#pragma unroll
    for (int off = 32; off > 0; off >>= 1)
        lsum += __shfl_down(lsum, off);
    if (lane == 0)
        partials[(b * NCHUNK + cy) * NSTRIPE + stripe] = lsum;
}

__global__ __launch_bounds__(256) void ssim_reduce(
    const float* __restrict__ partials, float* __restrict__ out)
{
    const int n = NSTRIPE * NCHUNK * NBATCH;  // 1920
    __shared__ double red[256];
    int tid = threadIdx.x;
    double s = 0.0;
    for (int i = tid; i < n; i += 256) s += (double)partials[i];
    red[tid] = s;
    __syncthreads();
    for (int k = 128; k > 0; k >>= 1) {
        if (tid < k) red[tid] += red[tid + k];
        __syncthreads();
    }
    if (tid == 0) {
        double mean = red[0] / (double)((size_t)NBATCH * OUT_H * OUT_W);
        out[0] = (float)((1.0 - mean) * 0.5);
    }
}

extern "C" void kernel_launch(void* const* d_in, const int* in_sizes, int n_in,
                              void* d_out, int out_size, void* d_ws, size_t ws_size,
                              hipStream_t stream)
{
    const float* img1 = (const float*)d_in[0];
    const float* img2 = (const float*)d_in[1];
    float* out = (float*)d_out;
    float* partials = (float*)d_ws;  // 1920 floats = 7.7 KB

    dim3 grid(NSTRIPE, NCHUNK, NBATCH);  // 6 x 10 x 32 = 1920 single-wave blocks
    ssim_main<<<grid, dim3(64), 0, stream>>>(img1, img2, partials);
    ssim_reduce<<<1, dim3(256), 0, stream>>>(partials, out);
}

// Round 12
// 129.594 us; speedup vs baseline: 2.4895x; 1.0363x over previous
//
#include <hip/hip_runtime.h>

#define IMG_H 480
#define IMG_W 640
#define OUT_H 470    // 480 - 10
#define OUT_W 630    // 640 - 10
#define NBATCH 32
#define SW 118       // output columns per wave (128 input cols - 10 halo)
#define NSTRIPE 6    // ceil(630 / 118)
#define RCH 47       // output rows per wave-chunk (47 * 10 = 470 exact)
#define NCHUNK 10
#define NROWS (RCH + 10)   // 57 input rows per chunk

#define SSIM_C1 1.0f // (0.01*100)^2
#define SSIM_C2 9.0f // (0.03*100)^2

typedef float v2f __attribute__((ext_vector_type(2)));

// Normalized 11-tap Gaussian (sigma=1.5), matches numpy fp32 window to ~1e-7 rel.
__device__ constexpr float WG[11] = {
    0.00102838f, 0.00759876f, 0.03600077f, 0.10936068f, 0.21300554f,
    0.26601173f,
    0.21300554f, 0.10936068f, 0.03600077f, 0.00759876f, 0.00102838f
};

// Packed fp32 fma: llvm.fma.v2f32 -> v_pk_fma_f32 (2 FLOP-pairs per issue slot)
__device__ __forceinline__ v2f pk_fma(v2f a, v2f b, v2f c) {
    return __builtin_elementwise_fma(a, b, c);
}

// One phase. NO DS: each lane loads its own 12-col window directly (6x float2
// per image, 8B-aligned, L1-served; neighbors' 6x overlap hits L1/L2, not HBM).
// pk math packed over the two OUTPUT columns (A,B): taps consume natural
// register pairs (even j -> stored pair, odd j -> .y/.x cross-pair select),
// so no repacking movs. Per phase: 77 pk (h-pass) + 55 pk (ring) + ~14 pk
// (epilogue) + 12 loads.
//   VMEM: row IT+1 loaded into pb[(PP+1)&1], consumed next phase (vmcnt
//         retires under ~400 VALU cycles).
// *** INDEXING MUST BE COMPILE-TIME (R10 lesson) *** PP is a post-unroll
// literal (22-step inner unroll: 22 ≡ 0 mod 11 and even -> P=PP%11 and
// parity=PP&1 valid for any runtime base). IT used only for addresses /
// wave-uniform bounds (runtime OK).
// REGISTER BUDGET (R4/R5/R7): ring 110 + pb 48 + ~35 working ≈ 195 live.
// __launch_bounds__(64,2) -> 256-reg cap. Sentinel: WRITE_SIZE ~60 KB.
#define STEP(IT, PP)                                                          \
  {                                                                           \
    const int P   = (PP) % 11;                                                \
    const int cur = (PP) & 1;                                                 \
    const int nxt = ((PP) + 1) & 1;                                           \
    /* 1. VMEM prefetch row IT+1 into pb[nxt] (clamped; tail overshoot ok) */ \
    {                                                                         \
      int gy = y0 + (IT) + 1; if (gy > IMG_H - 1) gy = IMG_H - 1;             \
      const float* __restrict__ r1 = p1 + gy * IMG_W + colA;                  \
      const float* __restrict__ r2 = p2 + gy * IMG_W + colA;                  \
      _Pragma("unroll")                                                       \
      for (int k = 0; k < 6; ++k) {                                           \
        pb[nxt][0][k] = *(const v2f*)(r1 + 2 * k);                            \
        pb[nxt][1][k] = *(const v2f*)(r2 + 2 * k);                            \
      }                                                                       \
    }                                                                         \
    /* 2. h-pass on pb[cur] (row IT), packed over output cols (A,B) */        \
    v2f h1  = (v2f){0.f,0.f}, h2  = (v2f){0.f,0.f};                           \
    v2f h11 = (v2f){0.f,0.f}, h22 = (v2f){0.f,0.f}, h12 = (v2f){0.f,0.f};     \
    _Pragma("unroll")                                                         \
    for (int j = 0; j < 11; ++j) {                                            \
      const v2f wj = (v2f){WG[j], WG[j]};                                     \
      v2f q1, q2;                                                             \
      if (j & 1) {                                                            \
        q1 = (v2f){pb[cur][0][j >> 1].y, pb[cur][0][(j >> 1) + 1].x};         \
        q2 = (v2f){pb[cur][1][j >> 1].y, pb[cur][1][(j >> 1) + 1].x};         \
      } else {                                                                \
        q1 = pb[cur][0][j >> 1];                                              \
        q2 = pb[cur][1][j >> 1];                                              \
      }                                                                       \
      const v2f t1 = wj * q1;                                                 \
      const v2f t2 = wj * q2;                                                 \
      h1 += t1; h2 += t2;                                                     \
      h11 = pk_fma(t1, q1, h11);                                              \
      h22 = pk_fma(t2, q2, h22);                                              \
      h12 = pk_fma(t1, q2, h12);                                              \
    }                                                                         \
    /* 3. vertical ring update: 5 pk_fma per slot */                          \
    _Pragma("unroll")                                                         \
    for (int sl = 0; sl < 11; ++sl) {                                         \
      const float wt = WG[(P - sl + 11) % 11];                                \
      const v2f wv = (v2f){wt, wt};                                           \
      acc[sl][0] = pk_fma(wv, h1,  acc[sl][0]);                               \
      acc[sl][1] = pk_fma(wv, h2,  acc[sl][1]);                               \
      acc[sl][2] = pk_fma(wv, h11, acc[sl][2]);                               \
      acc[sl][3] = pk_fma(wv, h22, acc[sl][3]);                               \
      acc[sl][4] = pk_fma(wv, h12, acc[sl][4]);                               \
    }                                                                         \
    /* 4. slot sc got its w[10] tap -> output row y = IT-10 completes */      \
    const int sc = (P + 1) % 11;                                              \
    if ((IT) >= 10 && (y0 + (IT) - 10) < OUT_H) {                             \
      const v2f m1 = acc[sc][0], m2 = acc[sc][1];                             \
      const v2f msq1 = m1 * m1, msq2 = m2 * m2, mu12 = m1 * m2;               \
      const v2f two = (v2f){2.f, 2.f};                                        \
      const v2f c1v = (v2f){SSIM_C1, SSIM_C1};                                \
      const v2f c2v = (v2f){SSIM_C2, SSIM_C2};                                \
      const v2f vA = pk_fma(two, acc[sc][4] - mu12, c2v);                     \
      const v2f vB = (acc[sc][2] - msq1) + (acc[sc][3] - msq2) + c2v;         \
      const v2f num = pk_fma(two, mu12, c1v) * vA;                            \
      const v2f den = (msq1 + msq2 + c1v) * vB;                               \
      if (validA) lsum = fmaf(num.x, __builtin_amdgcn_rcpf(den.x), lsum);     \
      if (validB) lsum = fmaf(num.y, __builtin_amdgcn_rcpf(den.y), lsum);     \
    }                                                                         \
    _Pragma("unroll")                                                         \
    for (int ch = 0; ch < 5; ++ch) acc[sc][ch] = (v2f){0.f, 0.f};             \
  }

__global__ __launch_bounds__(64, 2) void ssim_main(
    const float* __restrict__ img1,
    const float* __restrict__ img2,
    float* __restrict__ partials)
{
    const int lane   = threadIdx.x;
    const int stripe = blockIdx.x;
    const int cy     = blockIdx.y;
    const int b      = blockIdx.z;
    const int x0 = SW * stripe;
    const int y0 = RCH * cy;

    const float* __restrict__ p1 = img1 + (size_t)b * (IMG_H * IMG_W);
    const float* __restrict__ p2 = img2 + (size_t)b * (IMG_H * IMG_W);

    // lane's 12-col window base; clamp keeps cols colA..colA+11 in-bounds.
    // Any VALID output col c needs window c..c+10 with base c <= 628, so the
    // clamp is a no-op for valid lanes (it only moves invalid/edge lanes).
    int colA = x0 + 2 * lane;
    if (colA > IMG_W - 12) colA = IMG_W - 12;   // 628, even -> 8B aligned

    // lane l produces output cols x0+2l (A) and x0+2l+1 (B)
    const bool validA = (lane < 59) && (x0 + 2 * lane     < OUT_W);
    const bool validB = (lane < 59) && (x0 + 2 * lane + 1 < OUT_W);

    // vertical ring: 5 channels (mu1, mu2, s11, s22, s12), each v2f over (A,B)
    v2f acc[11][5];
#pragma unroll
    for (int i = 0; i < 11; ++i)
#pragma unroll
        for (int ch = 0; ch < 5; ++ch) acc[i][ch] = (v2f){0.f, 0.f};

    float lsum = 0.f;

    // input-row ping-pong: pb[parity][image][pair 0..5]
    v2f pb[2][2][6];

    // prologue: row 0 -> pb[0]
    {
        const float* __restrict__ r1 = p1 + y0 * IMG_W + colA;
        const float* __restrict__ r2 = p2 + y0 * IMG_W + colA;
#pragma unroll
        for (int k = 0; k < 6; ++k) {
            pb[0][0][k] = *(const v2f*)(r1 + 2 * k);
            pb[0][1][k] = *(const v2f*)(r2 + 2 * k);
        }
    }

    // 57 rows: 2 x 22-step unroll (22 ≡ 0 mod 11, even -> P/parity fold to
    // literals inside), then literal-base tail of 13 (44 % 11 == 0, 44 even).
    for (int blk = 0; blk < 2; ++blk) {
        const int base = 22 * blk;
#pragma unroll
        for (int p = 0; p < 22; ++p) STEP(base + p, p)
    }
#pragma unroll
    for (int p = 0; p < 13; ++p) STEP(44 + p, p)

    // wave-level reduction (64 lanes)
#pragma unroll
    for (int off = 32; off > 0; off >>= 1)
        lsum += __shfl_down(lsum, off);
    if (lane == 0)
        partials[(b * NCHUNK + cy) * NSTRIPE + stripe] = lsum;
}

__global__ __launch_bounds__(256) void ssim_reduce(
    const float* __restrict__ partials, float* __restrict__ out)
{
    const int n = NSTRIPE * NCHUNK * NBATCH;  // 1920
    __shared__ double red[256];
    int tid = threadIdx.x;
    double s = 0.0;
    for (int i = tid; i < n; i += 256) s += (double)partials[i];
    red[tid] = s;
    __syncthreads();
    for (int k = 128; k > 0; k >>= 1) {
        if (tid < k) red[tid] += red[tid + k];
        __syncthreads();
    }
    if (tid == 0) {
        double mean = red[0] / (double)((size_t)NBATCH * OUT_H * OUT_W);
        out[0] = (float)((1.0 - mean) * 0.5);
    }
}

extern "C" void kernel_launch(void* const* d_in, const int* in_sizes, int n_in,
                              void* d_out, int out_size, void* d_ws, size_t ws_size,
                              hipStream_t stream)
{
    const float* img1 = (const float*)d_in[0];
    const float* img2 = (const float*)d_in[1];
    float* out = (float*)d_out;
    float* partials = (float*)d_ws;  // 1920 floats = 7.7 KB

    dim3 grid(NSTRIPE, NCHUNK, NBATCH);  // 6 x 10 x 32 = 1920 single-wave blocks
    ssim_main<<<grid, dim3(64), 0, stream>>>(img1, img2, partials);
    ssim_reduce<<<1, dim3(256), 0, stream>>>(partials, out);
}